// Round 15
// baseline (98.963 us; speedup 1.0000x reference)
//
#include <hip/hip_runtime.h>

// Contrast MHSA: x,y:(4,1024,1024) f32; Wq/Wk/Wv:(1024,1024) f32
// out = (c_att, att) each (4,1024,1024) f32, concatenated (8388608 floats).
//
// r15 = r14 + V de-staging (m169 precedent: V slice is L2-resident at S=1024;
// LDS-staging it was pure overhead in learn_hip's attn — +26% when removed):
//  - V fragments read straight from global (V^T layout makes them contiguous
//    16B per lane), hoisted to loop top so L2 latency hides under phase A.
//  - LDS 48 -> 32 KB; staging gloads per barrier halved; -8 LDS reads/wave-mc.
//  - M0 hoist kept (r14); fminf(t,30) clamp LOAD-BEARING (r11: NaN without it).
// Pipeline:
//  1) cvt_all: f32 -> bf16 for x, y, Wq, Wk, Wv (+ zero M0)
//  2) gemm_proj: Q = (0.125*log2e)*(x Wq^T); K = x Wk^T; Vt = (y Wv^T)^T per head
//     (+ z=2 epilogue accumulates M0 column sums)
//  3) attn_fused (SINGLE PASS, Taylor-moment form, k=2):
//     dist = e/Z, e = exp(s), Z = sum e; sum_m dist_m = 1.
//     exp(+-d) ~ 1 +- d + d^2/2:  att = (M0 + M1/Z + M2/2Z^2)/den2,
//     c_att alternating signs; M_k = sum e^k v (MFMA), S_k row-sums via
//     ones-operand MFMA; e^2 fragment = elementwise square in-register.
//     4 waves x 32 q-rows (2 qg panels), 512 blocks, LDS 32 KB.

typedef __attribute__((ext_vector_type(8))) short bf16x8;
typedef __attribute__((ext_vector_type(4))) float f32x4;
typedef __attribute__((ext_vector_type(4))) float float4v;
typedef __attribute__((ext_vector_type(2))) unsigned int uint2v;
typedef __attribute__((ext_vector_type(4))) unsigned short ushort4v;

#define DEVINL static __device__ __forceinline__

DEVINL unsigned f2bf_u(float f) {
  unsigned u = __float_as_uint(f);
  return (u + 0x7fffu + ((u >> 16) & 1u)) >> 16;   // RNE
}
DEVINL unsigned short f2bf(float f) { return (unsigned short)f2bf_u(f); }
DEVINL unsigned pack2(float lo, float hi) { return f2bf_u(lo) | (f2bf_u(hi) << 16); }

DEVINL unsigned cvtpk(float lo, float hi) {       // v_cvt_pk_bf16_f32 (RNE, 1 inst)
  unsigned r; asm("v_cvt_pk_bf16_f32 %0, %1, %2" : "=v"(r) : "v"(lo), "v"(hi)); return r;
}

DEVINL float fexp2(float x) {        // guaranteed single v_exp_f32 (2^x)
  float r; asm("v_exp_f32 %0, %1" : "=v"(r) : "v"(x)); return r;
}

DEVINL void gload_lds16(const void* g, void* l) {
  __builtin_amdgcn_global_load_lds((const __attribute__((address_space(1))) unsigned int*)g,
                                   (__attribute__((address_space(3))) unsigned int*)l, 16, 0, 0);
}

DEVINL f32x4 mfma16(bf16x8 a, bf16x8 b, f32x4 c) {
  return __builtin_amdgcn_mfma_f32_16x16x32_bf16(a, b, c, 0, 0, 0);
}

// elementwise square of a bf16x8 fragment (PV A-fragments are per-lane element
// collections, so squaring the e-fragment IS the e^2-fragment)
DEVINL bf16x8 sq_frag(bf16x8 a) {
  union { bf16x8 h; unsigned u[4]; } ua; ua.h = a;
  union { unsigned u[4]; bf16x8 h; } ub;
#pragma unroll
  for (int d = 0; d < 4; ++d) {
    const float lo = __uint_as_float(ua.u[d] << 16);
    const float hi = __uint_as_float(ua.u[d] & 0xffff0000u);
    ub.u[d] = cvtpk(lo * lo, hi * hi);
  }
  return ub.h;
}

// ------------------------- 1) f32 -> bf16 convert (all 5 tensors) + M0 zero ----------
__global__ void cvt_all(const float* __restrict__ x, const float* __restrict__ y,
                        const float* __restrict__ wq, const float* __restrict__ wk,
                        const float* __restrict__ wv,
                        unsigned short* __restrict__ xb, unsigned short* __restrict__ yb,
                        unsigned short* __restrict__ wqb, unsigned short* __restrict__ wkb,
                        unsigned short* __restrict__ wvb, float* __restrict__ M0) {
  if (blockIdx.x < 8) {                         // zero M0[4][1024] (16 KB)
    const int idx = blockIdx.x * 512 + threadIdx.x * 2;
    M0[idx] = 0.f; M0[idx + 1] = 0.f;
  }
  long long e = (long long)blockIdx.x * 2048 + (long long)threadIdx.x * 8;
  const float* s; unsigned short* d; long long off;
  if (e < 4194304)       { s = x;  d = xb;  off = e; }
  else if (e < 8388608)  { s = y;  d = yb;  off = e - 4194304; }
  else if (e < 9437184)  { s = wq; d = wqb; off = e - 8388608; }
  else if (e < 10485760) { s = wk; d = wkb; off = e - 9437184; }
  else                   { s = wv; d = wvb; off = e - 10485760; }
  float4v a = *(const float4v*)(s + off);
  float4v b = *(const float4v*)(s + off + 4);
  ushort4v lo = { f2bf(a[0]), f2bf(a[1]), f2bf(a[2]), f2bf(a[3]) };
  ushort4v hi = { f2bf(b[0]), f2bf(b[1]), f2bf(b[2]), f2bf(b[3]) };
  *(ushort4v*)(d + off) = lo;
  *(ushort4v*)(d + off + 4) = hi;
}

// ------------------------- 2) projection GEMM -------------------------
__global__ __launch_bounds__(256, 3)
void gemm_proj(const unsigned short* __restrict__ xb, const unsigned short* __restrict__ yb,
               const unsigned short* __restrict__ wq, const unsigned short* __restrict__ wk,
               const unsigned short* __restrict__ wv,
               unsigned short* __restrict__ Qb, unsigned short* __restrict__ Kb,
               unsigned short* __restrict__ Vt, float* __restrict__ M0) {
  const int z = blockIdx.z;
  const unsigned short* A  = (z == 2) ? yb : xb;
  const unsigned short* Bw = (z == 0) ? wq : ((z == 1) ? wk : wv);

  __shared__ unsigned short lA[128 * 32];
  __shared__ unsigned short lB[128 * 32];

  const int tid = threadIdx.x;
  const int w = tid >> 6, l = tid & 63;
  const int lq = l & 15, lg = l >> 4;
  const int tm = blockIdx.y, tn = blockIdx.x;

  const int srow = l >> 2;
  const int scol = (l & 3) * 8;
  const size_t arow0 = (size_t)tm * 128 + w * 16 + srow;
  const size_t brow0 = (size_t)tn * 128 + w * 16 + srow;
  const int wr = (w >> 1) * 64, wc = (w & 1) * 64;

  f32x4 zero4 = {0.f, 0.f, 0.f, 0.f};
  f32x4 acc[4][4];
#pragma unroll
  for (int m = 0; m < 4; ++m)
#pragma unroll
    for (int n = 0; n < 4; ++n) acc[m][n] = zero4;

  for (int k0 = 0; k0 < 1024; k0 += 32) {
    gload_lds16(A + arow0 * 1024 + k0 + scol,        &lA[w * 512]);
    gload_lds16(A + (arow0 + 64) * 1024 + k0 + scol, &lA[w * 512 + 2048]);
    gload_lds16(Bw + brow0 * 1024 + k0 + scol,        &lB[w * 512]);
    gload_lds16(Bw + (brow0 + 64) * 1024 + k0 + scol, &lB[w * 512 + 2048]);
    __syncthreads();
    bf16x8 af[4], bfr[4];
#pragma unroll
    for (int m = 0; m < 4; ++m) af[m]  = *(const bf16x8*)&lA[(wr + m * 16 + lq) * 32 + lg * 8];
#pragma unroll
    for (int n = 0; n < 4; ++n) bfr[n] = *(const bf16x8*)&lB[(wc + n * 16 + lq) * 32 + lg * 8];
#pragma unroll
    for (int m = 0; m < 4; ++m)
#pragma unroll
      for (int n = 0; n < 4; ++n)
        acc[m][n] = mfma16(af[m], bfr[n], acc[m][n]);
    __syncthreads();
  }

  if (z < 2) {
    unsigned short* O = (z == 0) ? Qb : Kb;
    const float scale = (z == 0) ? 0.18033688011116012f : 1.0f;  // 0.125*log2e for Q
#pragma unroll
    for (int m = 0; m < 4; ++m)
#pragma unroll
      for (int n = 0; n < 4; ++n) {
        int row0 = tm * 128 + wr + m * 16 + lg * 4;
        int col  = tn * 128 + wc + n * 16 + lq;
#pragma unroll
        for (int j = 0; j < 4; ++j)
          O[(size_t)(row0 + j) * 1024 + col] = f2bf(acc[m][n][j] * scale);
      }
  } else {
#pragma unroll
    for (int m = 0; m < 4; ++m)
#pragma unroll
      for (int n = 0; n < 4; ++n) {
        int row0 = tm * 128 + wr + m * 16 + lg * 4;
        int col  = tn * 128 + wc + n * 16 + lq;
        int bb = row0 >> 10, n0 = row0 & 1023;
        uint2v p = { pack2(acc[m][n][0], acc[m][n][1]), pack2(acc[m][n][2], acc[m][n][3]) };
        *(uint2v*)(Vt + ((size_t)(bb * 1024 + col)) * 1024 + n0) = p;
      }
    // M0 column sums (sum over this block's 128 n-rows): per-thread sum over
    // (m,j), shfl-reduce over lg (rows), one atomicAdd per col from lanes lg==0.
    const int bb2 = tm >> 3;                     // block's batch (128 | 1024)
#pragma unroll
    for (int n = 0; n < 4; ++n) {
      float cs = 0.f;
#pragma unroll
      for (int m = 0; m < 4; ++m)
#pragma unroll
        for (int j = 0; j < 4; ++j) cs += acc[m][n][j];
      cs += __shfl_xor(cs, 16, 64);
      cs += __shfl_xor(cs, 32, 64);
      if (l < 16)
        atomicAdd(M0 + bb2 * 1024 + tn * 128 + wc + n * 16 + lq, cs);
    }
  }
}

// ------------------------- 3) attention helpers -------------------------
DEVINL void stage_tileK(const unsigned short* __restrict__ ghead, int m0,
                        unsigned short* tile, int w, int l) {
#pragma unroll
  for (int i = 0; i < 2; ++i) {
    const int c = i * 256 + w * 64 + l;
    const int row = c >> 3;
    const int col16 = (c & 7) ^ (row & 7);
    gload_lds16(ghead + (size_t)(m0 + row) * 1024 + col16 * 8,
                tile + (size_t)(i * 256 + w * 64) * 8);
  }
}
DEVINL bf16x8 lds_rd(const unsigned short* tile, int r, int g) {
  return *(const bf16x8*)((const char*)tile + (r << 7) + ((g ^ (r & 7)) << 4));
}

// ------------------------- 3) fused Taylor-moment attention -------------------------
// 512 blocks = (8 q-tiles of 128, 16 h, 4 b); 4 waves x 32 q-rows (2 qg panels).
// Per mc (64 kv): V fragments loaded from GLOBAL (L2-hot, hoisted before
// phase A so latency hides under QK+exp); K LDS-staged (XOR-swizzled, dbuf);
// QK -> e=exp2(min(t,30)) (clamp REQUIRED) -> e panel in per-wave LDS;
// phase B: a1 = e-frag, a2 = a1*a1 in-register; MFMAs per kst per qg:
// {S1,S2 (ones-B), 4 m1, 4 m2}. M0 read from global. LDS 32 KB.
__global__ __launch_bounds__(256, 2)
void attn_fused(const unsigned short* __restrict__ Qb, const unsigned short* __restrict__ Kb,
                const unsigned short* __restrict__ Vt, const float* __restrict__ M0,
                float* __restrict__ out) {
  __shared__ unsigned short Kl[2][4096];
  __shared__ unsigned short Pl[4][2048];   // per wave: 2 qg e-panels, 2048 B each

  const int tid = threadIdx.x;
  const int w = tid >> 6, l = tid & 63;
  const int lq = l & 15, lg = l >> 4;

  // Bijective XCD swizzle: 512 blocks, 64 consecutive vids per XCD.
  const int orig = blockIdx.x;
  const int vid = (orig & 7) * 64 + (orig >> 3);
  const int tile = vid & 7;
  const int h = (vid >> 3) & 15;
  const int b = vid >> 7;
  const int qBase = tile * 128 + w * 32;

  const unsigned short* Khead = Kb + ((size_t)b << 20) + h * 64;
  const unsigned short* VhG = Vt + ((size_t)(b * 1024 + h * 64)) * 1024;
  char* Pb = (char*)&Pl[w][0];

  // Q fragments (pre-scaled by 0.125*log2e): B-operand layout, q = lane&15
  bf16x8 qf[2][2];
#pragma unroll
  for (int qg = 0; qg < 2; ++qg)
#pragma unroll
    for (int kst = 0; kst < 2; ++kst)
      qf[qg][kst] = *(const bf16x8*)(Qb + ((size_t)(b * 1024 + qBase + qg * 16 + lq)) * 1024
                                        + h * 64 + kst * 32 + lg * 8);

  // all-ones bf16 fragment (layout-proof as B operand) — for S_k row sums
  union { short s[8]; bf16x8 v; } onesU;
#pragma unroll
  for (int i = 0; i < 8; ++i) onesU.s[i] = (short)0x3F80;
  const bf16x8 ones = onesU.v;

  f32x4 zero4 = {0.f, 0.f, 0.f, 0.f};
  f32x4 m1[2][4], m2[2][4];
  f32x4 s1a[2], s2a[2];
#pragma unroll
  for (int qg = 0; qg < 2; ++qg) {
    s1a[qg] = zero4; s2a[qg] = zero4;
#pragma unroll
    for (int dvg = 0; dvg < 4; ++dvg) { m1[qg][dvg] = zero4; m2[qg][dvg] = zero4; }
  }

  stage_tileK(Khead, 0, Kl[0], w, l);
  __syncthreads();

  for (int mc = 0; mc < 16; ++mc) {
    if (mc < 15) stage_tileK(Khead, (mc + 1) * 64, Kl[(mc + 1) & 1], w, l);
    const unsigned short* Kt = Kl[mc & 1];

    // hoisted V fragment loads (global, L2-hot): latency hides under phase A
    bf16x8 vfr[2][4];
#pragma unroll
    for (int kst = 0; kst < 2; ++kst)
#pragma unroll
      for (int dvg = 0; dvg < 4; ++dvg)
        vfr[kst][dvg] = *(const bf16x8*)(VhG + (size_t)(dvg * 16 + lq) * 1024
                                             + mc * 64 + kst * 32 + lg * 8);

    // phase A: QK -> e = exp2(min(t,30)); write bf16 e panel per qg
#pragma unroll
    for (int sub = 0; sub < 4; ++sub) {
      const int r = sub * 16 + lq;
      bf16x8 ka0 = lds_rd(Kt, r, lg);
      bf16x8 ka1 = lds_rd(Kt, r, 4 + lg);
      const int boff = lq * 128 + (((sub * 2 + (lg >> 1)) ^ (lq & 7)) << 4) + ((lg & 1) << 3);
#pragma unroll
      for (int qg = 0; qg < 2; ++qg) {
        f32x4 t = zero4;
        t = mfma16(ka0, qf[qg][0], t);
        t = mfma16(ka1, qf[qg][1], t);
        const float e0 = fexp2(fminf(t[0], 30.f)), e1 = fexp2(fminf(t[1], 30.f));
        const float e2 = fexp2(fminf(t[2], 30.f)), e3 = fexp2(fminf(t[3], 30.f));
        *(uint2v*)(Pb + qg * 2048 + boff) = (uint2v){ cvtpk(e0, e1), cvtpk(e2, e3) };
      }
    }

    // phase B: moment PV + S_k row-sums; e^2 fragment squared in-register
#pragma unroll
    for (int kst2 = 0; kst2 < 2; ++kst2) {
#pragma unroll
      for (int qg = 0; qg < 2; ++qg) {
        const int roff = qg * 2048 + lq * 128 + (((kst2 * 4 + lg) ^ (lq & 7)) << 4);
        bf16x8 a1 = *(const bf16x8*)(Pb + roff);
        bf16x8 a2 = sq_frag(a1);
        s1a[qg] = mfma16(a1, ones, s1a[qg]);
        s2a[qg] = mfma16(a2, ones, s2a[qg]);
#pragma unroll
        for (int dvg = 0; dvg < 4; ++dvg) {
          m1[qg][dvg] = mfma16(a1, vfr[kst2][dvg], m1[qg][dvg]);
          m2[qg][dvg] = mfma16(a2, vfr[kst2][dvg], m2[qg][dvg]);
        }
      }
    }
    __syncthreads();
  }

  // M0 (sum_n V) precomputed by gemm_proj: 4 L3-hot loads per lane
  float A0v[4];
#pragma unroll
  for (int dvg = 0; dvg < 4; ++dvg)
    A0v[dvg] = M0[b * 1024 + h * 64 + dvg * 16 + lq];

  // epilogue: S_k per-lane at row q' = lg*4+j; Taylor k=2 combine.
  // den2 = 1024 + 1 + S2/2Z^2 ; dena = 1024 - 1 + S2/2Z^2 (sum dist == 1).
#pragma unroll
  for (int qg = 0; qg < 2; ++qg)
#pragma unroll
    for (int j = 0; j < 4; ++j) {
      const float Z  = s1a[qg][j];
      const float iZ = 1.0f / Z;
      const float c2 = 0.5f * iZ * iZ;
      const float S2c2 = c2 * s2a[qg][j];
      const float r2 = 1.0f / (1025.0f + S2c2);
      const float ra = 1.0f / (1023.0f + S2c2);
      const int nrow = qBase + qg * 16 + lg * 4 + j;
      const size_t rb = ((size_t)(b * 1024 + nrow)) * 1024 + h * 64;
#pragma unroll
      for (int dvg = 0; dvg < 4; ++dvg) {
        const int dv = dvg * 16 + lq;
        const float A0 = A0v[dvg];
        const float A1 = m1[qg][dvg][j];
        const float A2 = m2[qg][dvg][j];
        const float num2 = A0 + iZ * A1 + c2 * A2;
        const float numa = A0 - iZ * A1 + c2 * A2;
        out[rb + dv] = numa * ra;                  // c_att (contrast branch)
        out[4194304 + rb + dv] = num2 * r2;        // att
      }
    }
}

// ------------------------- launch -------------------------
extern "C" void kernel_launch(void* const* d_in, const int* in_sizes, int n_in,
                              void* d_out, int out_size, void* d_ws, size_t ws_size,
                              hipStream_t stream) {
  const float* x  = (const float*)d_in[0];
  const float* y  = (const float*)d_in[1];
  const float* Wq = (const float*)d_in[2];
  const float* Wk = (const float*)d_in[3];
  const float* Wv = (const float*)d_in[4];
  float* out = (float*)d_out;
  char* ws = (char*)d_ws;
  const size_t MB = 1024 * 1024;
  unsigned short* xb  = (unsigned short*)(ws + 0 * MB);
  unsigned short* yb  = (unsigned short*)(ws + 8 * MB);
  unsigned short* wqb = (unsigned short*)(ws + 16 * MB);
  unsigned short* wkb = (unsigned short*)(ws + 18 * MB);
  unsigned short* wvb = (unsigned short*)(ws + 20 * MB);
  unsigned short* Qb  = (unsigned short*)(ws + 22 * MB);
  unsigned short* Kb  = (unsigned short*)(ws + 30 * MB);
  unsigned short* Vt  = (unsigned short*)(ws + 38 * MB);
  float*          M0  = (float*)(ws + 46 * MB);

  cvt_all<<<dim3(5632), dim3(256), 0, stream>>>(x, y, Wq, Wk, Wv, xb, yb, wqb, wkb, wvb, M0);

  gemm_proj<<<dim3(8, 32, 3), dim3(256), 0, stream>>>(xb, yb, wqb, wkb, wvb, Qb, Kb, Vt, M0);

  attn_fused<<<dim3(512), dim3(256), 0, stream>>>(Qb, Kb, Vt, M0, out);
}

// Round 16
// 92.346 us; speedup vs baseline: 1.0717x; 1.0717x over previous
//
#include <hip/hip_runtime.h>

// Contrast MHSA: x,y:(4,1024,1024) f32; Wq/Wk/Wv:(1024,1024) f32
// out = (c_att, att) each (4,1024,1024) f32, concatenated (8388608 floats).
//
// r16 = r14 (best verified: 93.6 us) + T5 setprio around phase-B MFMAs.
//  - r15's V de-staging REVERTED (global V loads serialize phase B: +6 us).
//  - M0 hoist kept (r14): M0 = sum_n V produced once in gemm z=2 epilogue.
//  - fminf(t,30) clamp LOAD-BEARING (r11 removed it -> NaN).
// Pipeline:
//  1) cvt_all: f32 -> bf16 for x, y, Wq, Wk, Wv (+ zero M0)
//  2) gemm_proj: Q = (0.125*log2e)*(x Wq^T); K = x Wk^T; Vt = (y Wv^T)^T per head
//     (+ z=2 epilogue accumulates M0 column sums)
//  3) attn_fused (SINGLE PASS, Taylor-moment form, k=2):
//     dist = e/Z, e = exp(s), Z = sum e; sum_m dist_m = 1.
//     exp(+-d) ~ 1 +- d + d^2/2:  att = (M0 + M1/Z + M2/2Z^2)/den2,
//     c_att alternating signs; M_k = sum e^k v (MFMA), S_k row-sums via
//     ones-operand MFMA; e^2 fragment = elementwise square in-register.
//     4 waves x 32 q-rows (2 qg panels), 512 blocks, LDS 48 KB.

typedef __attribute__((ext_vector_type(8))) short bf16x8;
typedef __attribute__((ext_vector_type(4))) float f32x4;
typedef __attribute__((ext_vector_type(4))) float float4v;
typedef __attribute__((ext_vector_type(2))) unsigned int uint2v;
typedef __attribute__((ext_vector_type(4))) unsigned short ushort4v;

#define DEVINL static __device__ __forceinline__

DEVINL unsigned f2bf_u(float f) {
  unsigned u = __float_as_uint(f);
  return (u + 0x7fffu + ((u >> 16) & 1u)) >> 16;   // RNE
}
DEVINL unsigned short f2bf(float f) { return (unsigned short)f2bf_u(f); }
DEVINL unsigned pack2(float lo, float hi) { return f2bf_u(lo) | (f2bf_u(hi) << 16); }

DEVINL unsigned cvtpk(float lo, float hi) {       // v_cvt_pk_bf16_f32 (RNE, 1 inst)
  unsigned r; asm("v_cvt_pk_bf16_f32 %0, %1, %2" : "=v"(r) : "v"(lo), "v"(hi)); return r;
}

DEVINL float fexp2(float x) {        // guaranteed single v_exp_f32 (2^x)
  float r; asm("v_exp_f32 %0, %1" : "=v"(r) : "v"(x)); return r;
}

DEVINL void gload_lds16(const void* g, void* l) {
  __builtin_amdgcn_global_load_lds((const __attribute__((address_space(1))) unsigned int*)g,
                                   (__attribute__((address_space(3))) unsigned int*)l, 16, 0, 0);
}

DEVINL f32x4 mfma16(bf16x8 a, bf16x8 b, f32x4 c) {
  return __builtin_amdgcn_mfma_f32_16x16x32_bf16(a, b, c, 0, 0, 0);
}

// elementwise square of a bf16x8 fragment (PV A-fragments are per-lane element
// collections, so squaring the e-fragment IS the e^2-fragment)
DEVINL bf16x8 sq_frag(bf16x8 a) {
  union { bf16x8 h; unsigned u[4]; } ua; ua.h = a;
  union { unsigned u[4]; bf16x8 h; } ub;
#pragma unroll
  for (int d = 0; d < 4; ++d) {
    const float lo = __uint_as_float(ua.u[d] << 16);
    const float hi = __uint_as_float(ua.u[d] & 0xffff0000u);
    ub.u[d] = cvtpk(lo * lo, hi * hi);
  }
  return ub.h;
}

// ------------------------- 1) f32 -> bf16 convert (all 5 tensors) + M0 zero ----------
__global__ void cvt_all(const float* __restrict__ x, const float* __restrict__ y,
                        const float* __restrict__ wq, const float* __restrict__ wk,
                        const float* __restrict__ wv,
                        unsigned short* __restrict__ xb, unsigned short* __restrict__ yb,
                        unsigned short* __restrict__ wqb, unsigned short* __restrict__ wkb,
                        unsigned short* __restrict__ wvb, float* __restrict__ M0) {
  if (blockIdx.x < 8) {                         // zero M0[4][1024] (16 KB)
    const int idx = blockIdx.x * 512 + threadIdx.x * 2;
    M0[idx] = 0.f; M0[idx + 1] = 0.f;
  }
  long long e = (long long)blockIdx.x * 2048 + (long long)threadIdx.x * 8;
  const float* s; unsigned short* d; long long off;
  if (e < 4194304)       { s = x;  d = xb;  off = e; }
  else if (e < 8388608)  { s = y;  d = yb;  off = e - 4194304; }
  else if (e < 9437184)  { s = wq; d = wqb; off = e - 8388608; }
  else if (e < 10485760) { s = wk; d = wkb; off = e - 9437184; }
  else                   { s = wv; d = wvb; off = e - 10485760; }
  float4v a = *(const float4v*)(s + off);
  float4v b = *(const float4v*)(s + off + 4);
  ushort4v lo = { f2bf(a[0]), f2bf(a[1]), f2bf(a[2]), f2bf(a[3]) };
  ushort4v hi = { f2bf(b[0]), f2bf(b[1]), f2bf(b[2]), f2bf(b[3]) };
  *(ushort4v*)(d + off) = lo;
  *(ushort4v*)(d + off + 4) = hi;
}

// ------------------------- 2) projection GEMM -------------------------
__global__ __launch_bounds__(256, 3)
void gemm_proj(const unsigned short* __restrict__ xb, const unsigned short* __restrict__ yb,
               const unsigned short* __restrict__ wq, const unsigned short* __restrict__ wk,
               const unsigned short* __restrict__ wv,
               unsigned short* __restrict__ Qb, unsigned short* __restrict__ Kb,
               unsigned short* __restrict__ Vt, float* __restrict__ M0) {
  const int z = blockIdx.z;
  const unsigned short* A  = (z == 2) ? yb : xb;
  const unsigned short* Bw = (z == 0) ? wq : ((z == 1) ? wk : wv);

  __shared__ unsigned short lA[128 * 32];
  __shared__ unsigned short lB[128 * 32];

  const int tid = threadIdx.x;
  const int w = tid >> 6, l = tid & 63;
  const int lq = l & 15, lg = l >> 4;
  const int tm = blockIdx.y, tn = blockIdx.x;

  const int srow = l >> 2;
  const int scol = (l & 3) * 8;
  const size_t arow0 = (size_t)tm * 128 + w * 16 + srow;
  const size_t brow0 = (size_t)tn * 128 + w * 16 + srow;
  const int wr = (w >> 1) * 64, wc = (w & 1) * 64;

  f32x4 zero4 = {0.f, 0.f, 0.f, 0.f};
  f32x4 acc[4][4];
#pragma unroll
  for (int m = 0; m < 4; ++m)
#pragma unroll
    for (int n = 0; n < 4; ++n) acc[m][n] = zero4;

  for (int k0 = 0; k0 < 1024; k0 += 32) {
    gload_lds16(A + arow0 * 1024 + k0 + scol,        &lA[w * 512]);
    gload_lds16(A + (arow0 + 64) * 1024 + k0 + scol, &lA[w * 512 + 2048]);
    gload_lds16(Bw + brow0 * 1024 + k0 + scol,        &lB[w * 512]);
    gload_lds16(Bw + (brow0 + 64) * 1024 + k0 + scol, &lB[w * 512 + 2048]);
    __syncthreads();
    bf16x8 af[4], bfr[4];
#pragma unroll
    for (int m = 0; m < 4; ++m) af[m]  = *(const bf16x8*)&lA[(wr + m * 16 + lq) * 32 + lg * 8];
#pragma unroll
    for (int n = 0; n < 4; ++n) bfr[n] = *(const bf16x8*)&lB[(wc + n * 16 + lq) * 32 + lg * 8];
#pragma unroll
    for (int m = 0; m < 4; ++m)
#pragma unroll
      for (int n = 0; n < 4; ++n)
        acc[m][n] = mfma16(af[m], bfr[n], acc[m][n]);
    __syncthreads();
  }

  if (z < 2) {
    unsigned short* O = (z == 0) ? Qb : Kb;
    const float scale = (z == 0) ? 0.18033688011116012f : 1.0f;  // 0.125*log2e for Q
#pragma unroll
    for (int m = 0; m < 4; ++m)
#pragma unroll
      for (int n = 0; n < 4; ++n) {
        int row0 = tm * 128 + wr + m * 16 + lg * 4;
        int col  = tn * 128 + wc + n * 16 + lq;
#pragma unroll
        for (int j = 0; j < 4; ++j)
          O[(size_t)(row0 + j) * 1024 + col] = f2bf(acc[m][n][j] * scale);
      }
  } else {
#pragma unroll
    for (int m = 0; m < 4; ++m)
#pragma unroll
      for (int n = 0; n < 4; ++n) {
        int row0 = tm * 128 + wr + m * 16 + lg * 4;
        int col  = tn * 128 + wc + n * 16 + lq;
        int bb = row0 >> 10, n0 = row0 & 1023;
        uint2v p = { pack2(acc[m][n][0], acc[m][n][1]), pack2(acc[m][n][2], acc[m][n][3]) };
        *(uint2v*)(Vt + ((size_t)(bb * 1024 + col)) * 1024 + n0) = p;
      }
    // M0 column sums (sum over this block's 128 n-rows): per-thread sum over
    // (m,j), shfl-reduce over lg (rows), one atomicAdd per col from lanes lg==0.
    const int bb2 = tm >> 3;                     // block's batch (128 | 1024)
#pragma unroll
    for (int n = 0; n < 4; ++n) {
      float cs = 0.f;
#pragma unroll
      for (int m = 0; m < 4; ++m)
#pragma unroll
        for (int j = 0; j < 4; ++j) cs += acc[m][n][j];
      cs += __shfl_xor(cs, 16, 64);
      cs += __shfl_xor(cs, 32, 64);
      if (l < 16)
        atomicAdd(M0 + bb2 * 1024 + tn * 128 + wc + n * 16 + lq, cs);
    }
  }
}

// ------------------------- 3) attention helpers -------------------------
DEVINL void stage_tileK(const unsigned short* __restrict__ ghead, int m0,
                        unsigned short* tile, int w, int l) {
#pragma unroll
  for (int i = 0; i < 2; ++i) {
    const int c = i * 256 + w * 64 + l;
    const int row = c >> 3;
    const int col16 = (c & 7) ^ (row & 7);
    gload_lds16(ghead + (size_t)(m0 + row) * 1024 + col16 * 8,
                tile + (size_t)(i * 256 + w * 64) * 8);
  }
}
DEVINL void stage_tileV(const unsigned short* __restrict__ ghead, int m0,
                        unsigned short* tile, int w, int l) {
#pragma unroll
  for (int i = 0; i < 2; ++i) {
    const int c = i * 256 + w * 64 + l;
    const int row = c >> 3;                       // row = dv
    const int col16 = (c & 7) ^ (row & 7);
    gload_lds16(ghead + (size_t)row * 1024 + m0 + col16 * 8,
                tile + (size_t)(i * 256 + w * 64) * 8);
  }
}
DEVINL bf16x8 lds_rd(const unsigned short* tile, int r, int g) {
  return *(const bf16x8*)((const char*)tile + (r << 7) + ((g ^ (r & 7)) << 4));
}

// ------------------------- 3) fused Taylor-moment attention -------------------------
// 512 blocks = (8 q-tiles of 128, 16 h, 4 b); 4 waves x 32 q-rows (2 qg panels).
// Per mc (64 kv): QK -> e=exp2(min(t,30)) (1 trans/score; clamp REQUIRED) ->
// e panel in per-wave LDS; phase B: a1 = e-frag, a2 = a1*a1 in-register;
// MFMAs per kst: per qg {S1,S2 (ones-B), 4 m1, 4 m2}, setprio(1)-wrapped (T5).
// M0 read from global. LDS 48 KB.
__global__ __launch_bounds__(256, 2)
void attn_fused(const unsigned short* __restrict__ Qb, const unsigned short* __restrict__ Kb,
                const unsigned short* __restrict__ Vt, const float* __restrict__ M0,
                float* __restrict__ out) {
  __shared__ unsigned short Kl[2][4096];
  __shared__ unsigned short Vl[2][4096];
  __shared__ unsigned short Pl[4][2048];   // per wave: 2 qg e-panels, 2048 B each

  const int tid = threadIdx.x;
  const int w = tid >> 6, l = tid & 63;
  const int lq = l & 15, lg = l >> 4;

  // Bijective XCD swizzle: 512 blocks, 64 consecutive vids per XCD.
  const int orig = blockIdx.x;
  const int vid = (orig & 7) * 64 + (orig >> 3);
  const int tile = vid & 7;
  const int h = (vid >> 3) & 15;
  const int b = vid >> 7;
  const int qBase = tile * 128 + w * 32;

  const unsigned short* Khead = Kb + ((size_t)b << 20) + h * 64;
  const unsigned short* Vhead = Vt + ((size_t)(b * 1024 + h * 64)) * 1024;
  char* Pb = (char*)&Pl[w][0];

  // Q fragments (pre-scaled by 0.125*log2e): B-operand layout, q = lane&15
  bf16x8 qf[2][2];
#pragma unroll
  for (int qg = 0; qg < 2; ++qg)
#pragma unroll
    for (int kst = 0; kst < 2; ++kst)
      qf[qg][kst] = *(const bf16x8*)(Qb + ((size_t)(b * 1024 + qBase + qg * 16 + lq)) * 1024
                                        + h * 64 + kst * 32 + lg * 8);

  // all-ones bf16 fragment (layout-proof as B operand) — for S_k row sums
  union { short s[8]; bf16x8 v; } onesU;
#pragma unroll
  for (int i = 0; i < 8; ++i) onesU.s[i] = (short)0x3F80;
  const bf16x8 ones = onesU.v;

  f32x4 zero4 = {0.f, 0.f, 0.f, 0.f};
  f32x4 m1[2][4], m2[2][4];
  f32x4 s1a[2], s2a[2];
#pragma unroll
  for (int qg = 0; qg < 2; ++qg) {
    s1a[qg] = zero4; s2a[qg] = zero4;
#pragma unroll
    for (int dvg = 0; dvg < 4; ++dvg) { m1[qg][dvg] = zero4; m2[qg][dvg] = zero4; }
  }

  stage_tileK(Khead, 0, Kl[0], w, l);
  stage_tileV(Vhead, 0, Vl[0], w, l);
  __syncthreads();

  for (int mc = 0; mc < 16; ++mc) {
    if (mc < 15) {
      stage_tileK(Khead, (mc + 1) * 64, Kl[(mc + 1) & 1], w, l);
      stage_tileV(Vhead, (mc + 1) * 64, Vl[(mc + 1) & 1], w, l);
    }
    const unsigned short* Kt  = Kl[mc & 1];
    const unsigned short* Vtl = Vl[mc & 1];

    // phase A: QK -> e = exp2(min(t,30)); write bf16 e panel per qg
#pragma unroll
    for (int sub = 0; sub < 4; ++sub) {
      const int r = sub * 16 + lq;
      bf16x8 ka0 = lds_rd(Kt, r, lg);
      bf16x8 ka1 = lds_rd(Kt, r, 4 + lg);
      const int boff = lq * 128 + (((sub * 2 + (lg >> 1)) ^ (lq & 7)) << 4) + ((lg & 1) << 3);
#pragma unroll
      for (int qg = 0; qg < 2; ++qg) {
        f32x4 t = zero4;
        t = mfma16(ka0, qf[qg][0], t);
        t = mfma16(ka1, qf[qg][1], t);
        const float e0 = fexp2(fminf(t[0], 30.f)), e1 = fexp2(fminf(t[1], 30.f));
        const float e2 = fexp2(fminf(t[2], 30.f)), e3 = fexp2(fminf(t[3], 30.f));
        *(uint2v*)(Pb + qg * 2048 + boff) = (uint2v){ cvtpk(e0, e1), cvtpk(e2, e3) };
      }
    }

    // phase B: moment PV + S_k row-sums; e^2 fragment squared in-register.
    // T5: setprio(1) keeps the MFMA wave favored while sibling waves stage.
#pragma unroll
    for (int kst2 = 0; kst2 < 2; ++kst2) {
      bf16x8 vf[4];
#pragma unroll
      for (int dvg = 0; dvg < 4; ++dvg)
        vf[dvg] = lds_rd(Vtl, dvg * 16 + lq, kst2 * 4 + lg);
#pragma unroll
      for (int qg = 0; qg < 2; ++qg) {
        const int roff = qg * 2048 + lq * 128 + (((kst2 * 4 + lg) ^ (lq & 7)) << 4);
        bf16x8 a1 = *(const bf16x8*)(Pb + roff);
        bf16x8 a2 = sq_frag(a1);
        __builtin_amdgcn_s_setprio(1);
        s1a[qg] = mfma16(a1, ones, s1a[qg]);
        s2a[qg] = mfma16(a2, ones, s2a[qg]);
#pragma unroll
        for (int dvg = 0; dvg < 4; ++dvg) {
          m1[qg][dvg] = mfma16(a1, vf[dvg], m1[qg][dvg]);
          m2[qg][dvg] = mfma16(a2, vf[dvg], m2[qg][dvg]);
        }
        __builtin_amdgcn_s_setprio(0);
      }
    }
    __syncthreads();
  }

  // M0 (sum_n V) precomputed by gemm_proj: 4 L3-hot loads per lane
  float A0v[4];
#pragma unroll
  for (int dvg = 0; dvg < 4; ++dvg)
    A0v[dvg] = M0[b * 1024 + h * 64 + dvg * 16 + lq];

  // epilogue: S_k per-lane at row q' = lg*4+j; Taylor k=2 combine.
  // den2 = 1024 + 1 + S2/2Z^2 ; dena = 1024 - 1 + S2/2Z^2 (sum dist == 1).
#pragma unroll
  for (int qg = 0; qg < 2; ++qg)
#pragma unroll
    for (int j = 0; j < 4; ++j) {
      const float Z  = s1a[qg][j];
      const float iZ = 1.0f / Z;
      const float c2 = 0.5f * iZ * iZ;
      const float S2c2 = c2 * s2a[qg][j];
      const float r2 = 1.0f / (1025.0f + S2c2);
      const float ra = 1.0f / (1023.0f + S2c2);
      const int nrow = qBase + qg * 16 + lg * 4 + j;
      const size_t rb = ((size_t)(b * 1024 + nrow)) * 1024 + h * 64;
#pragma unroll
      for (int dvg = 0; dvg < 4; ++dvg) {
        const int dv = dvg * 16 + lq;
        const float A0 = A0v[dvg];
        const float A1 = m1[qg][dvg][j];
        const float A2 = m2[qg][dvg][j];
        const float num2 = A0 + iZ * A1 + c2 * A2;
        const float numa = A0 - iZ * A1 + c2 * A2;
        out[rb + dv] = numa * ra;                  // c_att (contrast branch)
        out[4194304 + rb + dv] = num2 * r2;        // att
      }
    }
}

// ------------------------- launch -------------------------
extern "C" void kernel_launch(void* const* d_in, const int* in_sizes, int n_in,
                              void* d_out, int out_size, void* d_ws, size_t ws_size,
                              hipStream_t stream) {
  const float* x  = (const float*)d_in[0];
  const float* y  = (const float*)d_in[1];
  const float* Wq = (const float*)d_in[2];
  const float* Wk = (const float*)d_in[3];
  const float* Wv = (const float*)d_in[4];
  float* out = (float*)d_out;
  char* ws = (char*)d_ws;
  const size_t MB = 1024 * 1024;
  unsigned short* xb  = (unsigned short*)(ws + 0 * MB);
  unsigned short* yb  = (unsigned short*)(ws + 8 * MB);
  unsigned short* wqb = (unsigned short*)(ws + 16 * MB);
  unsigned short* wkb = (unsigned short*)(ws + 18 * MB);
  unsigned short* wvb = (unsigned short*)(ws + 20 * MB);
  unsigned short* Qb  = (unsigned short*)(ws + 22 * MB);
  unsigned short* Kb  = (unsigned short*)(ws + 30 * MB);
  unsigned short* Vt  = (unsigned short*)(ws + 38 * MB);
  float*          M0  = (float*)(ws + 46 * MB);

  cvt_all<<<dim3(5632), dim3(256), 0, stream>>>(x, y, Wq, Wk, Wv, xb, yb, wqb, wkb, wvb, M0);

  gemm_proj<<<dim3(8, 32, 3), dim3(256), 0, stream>>>(xb, yb, wqb, wkb, wvb, Qb, Kb, Vt, M0);

  attn_fused<<<dim3(512), dim3(256), 0, stream>>>(Qb, Kb, Vt, M0, out);
}